// Round 23
// baseline (650.160 us; speedup 1.0000x reference)
//
#include <hip/hip_runtime.h>
#include <hip/hip_bf16.h>

#define TT 512
#define MCELLS 16384            // B*N = 256*64
#define LOG2E 1.44269504088896340736f
#define LN2   0.69314718055994530942f

typedef __attribute__((ext_vector_type(8))) short bf16x8;
typedef __attribute__((ext_vector_type(4))) float f32x4;
typedef __attribute__((ext_vector_type(4))) unsigned u32x4;

__device__ __forceinline__ short f2bf(float f) {
    __hip_bfloat16 h = __float2bfloat16(f);
    return __builtin_bit_cast(short, h);
}
// two f32 -> packed bf16 dword (low16 = a, high16 = b), RNE in HW
__device__ __forceinline__ unsigned cvtpk(float a, float b) {
    unsigned r;
    asm("v_cvt_pk_bf16_f32 %0, %1, %2" : "=v"(r) : "v"(a), "v"(b));
    return r;
}

// Persistent LSTM. grid = 1024 blocks x 256 threads (4 waves) = 4 blocks/CU
// over all 256 CUs, 4 waves/SIMD.
// Block owns 16 cells (cell = blockIdx*16 + (lane&15)); wave w handles hdims
// [w*16, w*16+16) for all 4 gates (jm tile = gate*4 + w). Swapped MFMA
// D[gate-rows, cell], A = W_hh VGPR-resident, B = h^T from LDS. K=96: 3rd
// MFMA carries x*W_ih + bias (B-ext rows [x,1]).
// Validated: conditional g-dot MFMA 1-in-4 steps (R14/R15); LDS-only loop
// barrier (R17); nearest-point f32 tanh LUT delta=1/512 (R18); sigma_i/o via
// the same table (R19); time loop unrolled x2 (R20). sigma_f stays exp2+rcp
// (the three ~3e-2 LUT failures R8/R9/R11 all had sigma_f in LUT; R19's
// sigma_i/o arm passed). Phase skew (R21) was null -- removed.
// NEW (R22): tanh(cp) -- the ONLY LDS gather on the loop-carried recurrence
// path -- replaced by the exp2 identity tc = 1 - 2*rcp(1+exp2(2*log2e*cp))
// (graceful saturation, no clamp). Swaps ~120-250 cyc of loaded-gather
// latency for a ~45-cyc trans chain and cuts LUT gathers 4->3 per elem.
// tg/si/so stay LUT (parallel, off the carried chain).
__global__ __launch_bounds__(256, 4)
void lstm_net_kernel(const float* __restrict__ input,
                     const float* __restrict__ w1,
                     const float* __restrict__ b1,
                     const float* __restrict__ w2,
                     const float* __restrict__ b2,
                     const float* __restrict__ W_ih,
                     const float* __restrict__ W_hh,
                     const float* __restrict__ b_ih,
                     const float* __restrict__ b_hh,
                     const float* __restrict__ wg,
                     const float* __restrict__ bg,
                     float* __restrict__ out)
{
    __shared__ float tabT[8192];        // tanh((i-4096)/512), i = 0..8191
    // h double buffer: 2 x 16 rows(cells) x 144B (64 bf16 + pad)
    __shared__ __align__(16) char hbuf[2 * 16 * 144];

// tanh LUT: nearest-point, direct indexing. i = round(512*x) + 4096.
#define LUT_TANH(xv, dst) {                                              \
    const float _c = __builtin_amdgcn_fmed3f((xv), -8.0f, 7.998046875f); \
    const float _u = fmaf(_c, 512.0f, 4096.5f);                          \
    const int   _i = (int)_u;                                            \
    (dst) = tabT[_i]; }
// sigmoid via the SAME table: sigma(x) = 0.5 + 0.5*tanh(x/2);
// index = round(256*x) + 4096, domain [-16,16).
#define LUT_SIGT(xv, dst) {                                              \
    const float _c = __builtin_amdgcn_fmed3f((xv), -16.0f, 15.99609375f);\
    const float _u = fmaf(_c, 256.0f, 4096.5f);                          \
    const int   _i = (int)_u;                                            \
    (dst) = fmaf(0.5f, tabT[_i], 0.5f); }

    const int tid  = threadIdx.x;
    const int wv   = tid >> 6;          // 0..3: 16-hdim slice
    const int lane = tid & 63;
    const int lo   = lane & 15;
    const int hi   = lane >> 4;

    // ---- build tanh table (one-time): tanh on [-8, 8), step 1/512 ----
    for (int idx = tid; idx < 8192; idx += 256) {
        const float xv = (float)(idx - 4096) * 0.001953125f;
        const float e  = __builtin_amdgcn_exp2f(2.0f * LOG2E * xv);
        tabT[idx] = 1.0f - 2.0f / (1.0f + e);
    }

    for (int o = tid; o < (2 * 16 * 144) / 4; o += 256)
        ((unsigned*)hbuf)[o] = 0u;      // h0 = 0 (both buffers)

    // ---- per-cell constants ----
    const int cell = blockIdx.x * 16 + lo;
    const int n    = cell & 63;
    float a_n = 0.f, c_n = 0.f;
    #pragma unroll
    for (int k = 0; k < 10; ++k) {
        a_n += w1[n * 10 + k] * w2[n * 10 + k];   // per-neuron affine collapse
        c_n += b1[n * 10 + k] * w2[n * 10 + k];
    }
    c_n += b2[n];
    const float bgv = bg[0];

    // ---- A-fragments resident in VGPRs (K=96 incl bias-ext) ----
    bf16x8 AWf[4][3];
    #pragma unroll
    for (int g = 0; g < 4; ++g) {
        const int row = (g * 4 + wv) * 16 + lo;
        #pragma unroll
        for (int kk = 0; kk < 2; ++kk) {
            const float* src = W_hh + row * 64 + kk * 32 + hi * 8;
            bf16x8 v;
            #pragma unroll
            for (int e = 0; e < 8; ++e) v[e] = f2bf(src[e]);
            AWf[g][kk] = v;
        }
        bf16x8 vx = {};                 // K-ext: col64 = W_ih, col65 = bias
        if (hi == 0) {
            vx[0] = f2bf(W_ih[row]);
            vx[1] = f2bf(b_ih[row] + b_hh[row]);
        }
        AWf[g][2] = vx;
    }
    // g-dot A-frags: row 0 = wg (lanes lo==0), rows 1..15 = 0
    bf16x8 AWg[2];
    #pragma unroll
    for (int kk = 0; kk < 2; ++kk) {
        bf16x8 v = {};
        if (lo == 0) {
            const float* src = wg + kk * 32 + hi * 8;
            #pragma unroll
            for (int e = 0; e < 8; ++e) v[e] = f2bf(src[e]);
        }
        AWg[kk] = v;
    }

    const f32x4 zero4 = {0.f, 0.f, 0.f, 0.f};
    f32x4 cst = zero4;                  // c state (4 elems/lane)
    float sp0 = 0.f;                    // softplus at t=0 (held by wave 1)
    float gA  = 0.f;                    // g delay register
    const float* inP  = input + cell;
    float*       outP = out + cell;
    float raw_next = inP[0];

    __syncthreads();                    // one-time full sync: table + h0

// One LSTM step. tt = step index; RDOFF/WROFF = compile-time buffer offsets.
#define STEP(tt, RDOFF, WROFF) {                                             \
        const float raw = raw_next;                                          \
        raw_next = inP[(((tt) + 1) & (TT - 1)) * MCELLS];                     \
        const float x = raw * a_n + c_n;                                      \
        u32x4 bxi = {0u, 0u, 0u, 0u};                                         \
        bxi[0] = (hi == 0) ? cvtpk(x, 1.0f) : 0u;                             \
        const bf16x8 bx = __builtin_bit_cast(bf16x8, bxi);                    \
        const char* hrd = hbuf + (RDOFF) + lo * 144;                          \
        const bf16x8 bf0 = *(const bf16x8*)(hrd + hi * 16);                   \
        const bf16x8 bf1 = *(const bf16x8*)(hrd + 64 + hi * 16);              \
        if (((((tt) + 1) & 3) == wv) || ((tt) == 1 && wv == 1)) {             \
            f32x4 accg;                                                       \
            accg = __builtin_amdgcn_mfma_f32_16x16x32_bf16(AWg[0], bf0, zero4, 0, 0, 0); \
            accg = __builtin_amdgcn_mfma_f32_16x16x32_bf16(AWg[1], bf1, accg, 0, 0, 0);  \
            gA = accg[0];                                                     \
        }                                                                     \
        f32x4 acc[4];                                                         \
        _Pragma("unroll")                                                     \
        for (int g = 0; g < 4; ++g) {                                         \
            acc[g] = __builtin_amdgcn_mfma_f32_16x16x32_bf16(AWf[g][2], bx,  zero4, 0, 0, 0);  \
            acc[g] = __builtin_amdgcn_mfma_f32_16x16x32_bf16(AWf[g][0], bf0, acc[g], 0, 0, 0); \
            acc[g] = __builtin_amdgcn_mfma_f32_16x16x32_bf16(AWf[g][1], bf1, acc[g], 0, 0, 0); \
        }                                                                     \
        float hv[4];                                                          \
        _Pragma("unroll")                                                     \
        for (int r = 0; r < 4; ++r) {                                         \
            const float ip = acc[0][r];                                       \
            const float fp = acc[1][r];                                       \
            const float gp = acc[2][r];                                       \
            const float op = acc[3][r];                                       \
            const float Ef = __builtin_amdgcn_exp2f(-LOG2E * fp);             \
            float si, so, tg;                                                 \
            LUT_SIGT(ip, si);                                                 \
            LUT_SIGT(op, so);                                                 \
            LUT_TANH(gp, tg);                                                 \
            const float sf = __builtin_amdgcn_rcpf(1.f + Ef);                 \
            const float cp = fmaf(sf, cst[r], si * tg);                       \
            cst[r] = cp;                                                      \
            /* tanh(cp) via exp2 identity: keeps the carried chain off LDS */ \
            const float Ec = __builtin_amdgcn_exp2f(2.f * LOG2E * cp);        \
            const float tc = 1.f - 2.f * __builtin_amdgcn_rcpf(1.f + Ec);     \
            hv[r] = so * tc;                                                  \
        }                                                                     \
        uint2 pk;                                                             \
        pk.x = cvtpk(hv[0], hv[1]);                                           \
        pk.y = cvtpk(hv[2], hv[3]);                                           \
        *(uint2*)(hbuf + (WROFF) + lo * 144 + wv * 32 + hi * 8) = pk;         \
        if ((((tt) == 0) ? (wv == 1) : (((tt) & 3) == wv)) && hi == 0) {      \
            const float spE = __builtin_amdgcn_exp2f(LOG2E * (x - 1.f));      \
            const float sp  = LN2 * __builtin_amdgcn_logf(1.f + spE);         \
            if ((tt) == 0) {                                                  \
                sp0 = sp;                                                     \
            } else if ((tt) == 1) {                                           \
                outP[MCELLS] = sp;                                            \
                outP[0] = (gA + bgv) * sp0;                                   \
            } else {                                                          \
                outP[(tt) * MCELLS] = (gA + bgv) * sp;                        \
            }                                                                 \
        }                                                                     \
        asm volatile("s_waitcnt lgkmcnt(0)\n\ts_barrier" ::: "memory");       \
    }

    for (int t = 0; t < TT; t += 2) {
        STEP(t,     0,    2304);        // read buf0, write buf1
        STEP(t + 1, 2304, 0);           // read buf1, write buf0
    }
#undef STEP
#undef LUT_TANH
#undef LUT_SIGT
}

extern "C" void kernel_launch(void* const* d_in, const int* in_sizes, int n_in,
                              void* d_out, int out_size, void* d_ws, size_t ws_size,
                              hipStream_t stream) {
    const float* input = (const float*)d_in[0];
    const float* w1    = (const float*)d_in[1];
    const float* b1    = (const float*)d_in[2];
    const float* w2    = (const float*)d_in[3];
    const float* b2    = (const float*)d_in[4];
    const float* W_ih  = (const float*)d_in[5];
    const float* W_hh  = (const float*)d_in[6];
    const float* b_ih  = (const float*)d_in[7];
    const float* b_hh  = (const float*)d_in[8];
    const float* wg    = (const float*)d_in[9];
    const float* bg    = (const float*)d_in[10];

    lstm_net_kernel<<<dim3(1024), dim3(256), 0, stream>>>(
        input, w1, b1, w2, b2, W_ih, W_hh, b_ih, b_hh, wg, bg, (float*)d_out);
}